// Round 1
// baseline (1718.477 us; speedup 1.0000x reference)
//
#include <hip/hip_runtime.h>
#include <hip/hip_bf16.h>
#include <math.h>

#define S_LEN 2048
#define HIDD  2048
#define NHEAD 16
#define HD    128     // head dim for q/k/v (KD == VHD == 128)

constexpr int BM = 128, BN = 128, BK = 16;

__device__ __forceinline__ float silu_f(float x) {
    return x / (1.f + expf(-x));
}

// MODE 0: C = x @ [Wq|Wk|Wv|Wg]; xpos epilogue on q/k; head-major scatter q/k/v; g row-major
// MODE 1: C = A @ W0 -> outC row-major
template<int MODE>
__global__ __launch_bounds__(256)
void gemm_kernel(const float* __restrict__ A,
                 const float* __restrict__ W0, const float* __restrict__ W1,
                 const float* __restrict__ W2, const float* __restrict__ W3,
                 const int* __restrict__ pos_ids,
                 float* __restrict__ qh, float* __restrict__ kh,
                 float* __restrict__ vh, float* __restrict__ gbuf,
                 float* __restrict__ outC)
{
    __shared__ float As[BK][BM + 4];   // +4 pad: conflict-free transposed stores, keeps 16B align
    __shared__ float Bs[BK][BN];

    const int tid = threadIdx.x;
    const int tx = tid & 15, ty = tid >> 4;
    const int n0 = blockIdx.x * BN;
    const int m0 = blockIdx.y * BM;

    const float* Bp;
    int nn;
    if (MODE == 0) {
        const int sel = n0 >> 11;          // 0:q 1:k 2:v 3:g  (2048 cols each)
        nn = n0 & 2047;
        Bp = (sel == 0) ? W0 : (sel == 1) ? W1 : (sel == 2) ? W2 : W3;
    } else {
        Bp = W0;
        nn = n0;
    }

    float acc[8][8];
    #pragma unroll
    for (int i = 0; i < 8; i++)
        #pragma unroll
        for (int j = 0; j < 8; j++) acc[i][j] = 0.f;

    const int arow = tid >> 2;        // 0..63
    const int ac4  = (tid & 3) * 4;   // 0,4,8,12 : k-offset of this thread's A float4
    const int bk   = tid >> 5;        // 0..7
    const int bc4  = (tid & 31) * 4;  // 0..124

    const float* Aptr0 = A + (size_t)(m0 + arow) * HIDD + ac4;
    const float* Aptr1 = Aptr0 + (size_t)64 * HIDD;
    const float* Bptr0 = Bp + (size_t)bk * HIDD + nn + bc4;
    const float* Bptr1 = Bptr0 + (size_t)8 * HIDD;

    for (int k0 = 0; k0 < HIDD; k0 += BK) {
        const float4 a0 = *(const float4*)(Aptr0 + k0);
        const float4 a1 = *(const float4*)(Aptr1 + k0);
        const float4 b0 = *(const float4*)(Bptr0 + (size_t)k0 * HIDD);
        const float4 b1 = *(const float4*)(Bptr1 + (size_t)k0 * HIDD);
        __syncthreads();   // previous tile's compute done before overwrite
        As[ac4 + 0][arow] = a0.x; As[ac4 + 1][arow] = a0.y;
        As[ac4 + 2][arow] = a0.z; As[ac4 + 3][arow] = a0.w;
        As[ac4 + 0][arow + 64] = a1.x; As[ac4 + 1][arow + 64] = a1.y;
        As[ac4 + 2][arow + 64] = a1.z; As[ac4 + 3][arow + 64] = a1.w;
        *(float4*)&Bs[bk][bc4]     = b0;
        *(float4*)&Bs[bk + 8][bc4] = b1;
        __syncthreads();
        #pragma unroll
        for (int kk = 0; kk < BK; kk++) {
            const float4 av0 = *(const float4*)&As[kk][ty * 4];
            const float4 av1 = *(const float4*)&As[kk][ty * 4 + 64];
            const float4 bv0 = *(const float4*)&Bs[kk][tx * 4];
            const float4 bv1 = *(const float4*)&Bs[kk][tx * 4 + 64];
            const float am[8]  = {av0.x, av0.y, av0.z, av0.w, av1.x, av1.y, av1.z, av1.w};
            const float bn_[8] = {bv0.x, bv0.y, bv0.z, bv0.w, bv1.x, bv1.y, bv1.z, bv1.w};
            #pragma unroll
            for (int i = 0; i < 8; i++)
                #pragma unroll
                for (int j = 0; j < 8; j++)
                    acc[i][j] = fmaf(am[i], bn_[j], acc[i][j]);
        }
    }

    if (MODE == 1) {
        #pragma unroll
        for (int i = 0; i < 8; i++) {
            const int r = m0 + ((i >> 2) << 6) + ty * 4 + (i & 3);
            #pragma unroll
            for (int jh = 0; jh < 2; jh++) {
                const float4 o = make_float4(acc[i][jh * 4 + 0], acc[i][jh * 4 + 1],
                                             acc[i][jh * 4 + 2], acc[i][jh * 4 + 3]);
                *(float4*)&outC[(size_t)r * HIDD + n0 + jh * 64 + tx * 4] = o;
            }
        }
        return;
    }

    // MODE 0 epilogue
    const int sel = n0 >> 11;
    if (sel >= 2) {
        #pragma unroll
        for (int i = 0; i < 8; i++) {
            const int r = m0 + ((i >> 2) << 6) + ty * 4 + (i & 3);
            #pragma unroll
            for (int jh = 0; jh < 2; jh++) {
                const float4 o = make_float4(acc[i][jh * 4 + 0], acc[i][jh * 4 + 1],
                                             acc[i][jh * 4 + 2], acc[i][jh * 4 + 3]);
                const int c = tx * 4 + jh * 64;         // 0..127 within the 128-wide tile
                if (sel == 2) {
                    const int h = nn >> 7;              // one head per 128-col tile
                    *(float4*)&vh[((size_t)h * S_LEN + r) * HD + c] = o;
                } else {
                    *(float4*)&gbuf[(size_t)r * HIDD + nn + c] = o;
                }
            }
        }
    } else {
        float* dst = (sel == 0) ? qh : kh;
        const float sgn = (sel == 0) ? 1.f : -1.f;      // k uses downscale (1/scale)
        const int h = nn >> 7;
        #pragma unroll
        for (int i = 0; i < 8; i++) {
            const int r = m0 + ((i >> 2) << 6) + ty * 4 + (i & 3);
            const float posf = (float)pos_ids[r];
            const float pexp = sgn * posf * (1.f / 512.f);
            #pragma unroll
            for (int jh = 0; jh < 2; jh++) {
                const int d0 = tx * 4 + jh * 64;        // even, within-head dim
                const float v0 = acc[i][jh * 4 + 0], v1 = acc[i][jh * 4 + 1];
                const float v2 = acc[i][jh * 4 + 2], v3 = acc[i][jh * 4 + 3];
                // pair (d0, d0+1): inv_freq = 10000^(-d0/128), xs = (d0 + 0.4*128)/(1.4*128)
                const float ang_a = posf * powf(10000.f, -(float)d0 * (1.f / 128.f));
                float sa, ca; sincosf(ang_a, &sa, &ca);
                const float scl_a = powf(((float)d0 + 51.2f) * (1.f / 179.2f), pexp);
                const float e0 = (v0 * ca - v1 * sa) * scl_a;
                const float e1 = (v1 * ca + v0 * sa) * scl_a;
                // pair (d0+2, d0+3)
                const float ang_b = posf * powf(10000.f, -(float)(d0 + 2) * (1.f / 128.f));
                float sb, cb; sincosf(ang_b, &sb, &cb);
                const float scl_b = powf(((float)(d0 + 2) + 51.2f) * (1.f / 179.2f), pexp);
                const float e2 = (v2 * cb - v3 * sb) * scl_b;
                const float e3 = (v3 * cb + v2 * sb) * scl_b;
                *(float4*)&dst[((size_t)h * S_LEN + r) * HD + d0] = make_float4(e0, e1, e2, e3);
            }
        }
    }
}

// Retention (causal decayed attention, no softmax) + fused groupnorm + silu(g) gate.
// Block: (head h, 64 q-rows). Chunks of 32 k-rows. 256 threads.
__global__ __launch_bounds__(256)
void retention_kernel(const float* __restrict__ qh, const float* __restrict__ kh,
                      const float* __restrict__ vh, const float* __restrict__ gbuf,
                      const float* __restrict__ gnw, const float* __restrict__ gnb,
                      float* __restrict__ y)
{
    constexpr int QT = 64, KT = 32;
    __shared__ float qs[QT][HD + 4];
    __shared__ float ks[KT][HD + 4];
    __shared__ float vs[KT][HD];
    __shared__ float ss[QT][KT + 1];
    __shared__ float redm[QT], redi[QT];

    const int h  = blockIdx.y;
    const int qb = blockIdx.x;
    const int r0 = qb * QT;
    const int tid = threadIdx.x;
    const int tx = tid & 15, ty = tid >> 4;

    // log(gamma_h), gamma = 1 - exp(linspace(log(1/32), log(1/512), 16))
    const float e  = -3.4657359f + (float)h * ((-6.2383246f + 3.4657359f) / 15.f);
    const float lg = logf(1.f - expf(e));

    const float* qbase = qh + ((size_t)h * S_LEN + r0) * HD;
    for (int f4 = tid; f4 < QT * HD / 4; f4 += 256) {
        const int row = f4 >> 5, c = (f4 & 31) * 4;
        *(float4*)&qs[row][c] = *(const float4*)&qbase[row * HD + c];
    }

    float outv[4][8];
    #pragma unroll
    for (int i = 0; i < 4; i++)
        #pragma unroll
        for (int j = 0; j < 8; j++) outv[i][j] = 0.f;

    const float* kbase = kh + (size_t)h * S_LEN * HD;
    const float* vbase = vh + (size_t)h * S_LEN * HD;
    const int nch = (r0 + QT) / KT;

    __syncthreads();
    for (int ch = 0; ch < nch; ch++) {
        const int kg0 = ch * KT;
        for (int f4 = tid; f4 < KT * HD / 4; f4 += 256) {
            const int row = f4 >> 5, c = (f4 & 31) * 4;
            *(float4*)&ks[row][c] = *(const float4*)&kbase[(size_t)(kg0 + row) * HD + c];
            *(float4*)&vs[row][c] = *(const float4*)&vbase[(size_t)(kg0 + row) * HD + c];
        }
        __syncthreads();

        // scores: 4 q-rows x 2 k-cols per thread
        float sc[4][2] = {{0.f, 0.f}, {0.f, 0.f}, {0.f, 0.f}, {0.f, 0.f}};
        #pragma unroll 4
        for (int d = 0; d < HD; d += 4) {
            const float4 k0 = *(const float4*)&ks[tx * 2][d];
            const float4 k1 = *(const float4*)&ks[tx * 2 + 1][d];
            #pragma unroll
            for (int i = 0; i < 4; i++) {
                const float4 qv = *(const float4*)&qs[ty * 4 + i][d];
                sc[i][0] = fmaf(qv.x, k0.x, fmaf(qv.y, k0.y, fmaf(qv.z, k0.z, fmaf(qv.w, k0.w, sc[i][0]))));
                sc[i][1] = fmaf(qv.x, k1.x, fmaf(qv.y, k1.y, fmaf(qv.z, k1.z, fmaf(qv.w, k1.w, sc[i][1]))));
            }
        }
        // decay + causal mask, stage to LDS
        #pragma unroll
        for (int i = 0; i < 4; i++) {
            const int qg = r0 + ty * 4 + i;
            #pragma unroll
            for (int j = 0; j < 2; j++) {
                const int kg = kg0 + tx * 2 + j;
                const int dq = qg - kg;
                const float dec = (dq >= 0) ? __expf(lg * (float)dq) : 0.f;
                ss[ty * 4 + i][tx * 2 + j] = sc[i][j] * dec;
            }
        }
        __syncthreads();

        // PV accumulate: 4 q-rows x 8 v-cols (tx*4 and tx*4+64)
        #pragma unroll 4
        for (int k = 0; k < KT; k++) {
            const float4 v0 = *(const float4*)&vs[k][tx * 4];
            const float4 v1 = *(const float4*)&vs[k][tx * 4 + 64];
            #pragma unroll
            for (int i = 0; i < 4; i++) {
                const float s = ss[ty * 4 + i][k];
                outv[i][0] = fmaf(s, v0.x, outv[i][0]);
                outv[i][1] = fmaf(s, v0.y, outv[i][1]);
                outv[i][2] = fmaf(s, v0.z, outv[i][2]);
                outv[i][3] = fmaf(s, v0.w, outv[i][3]);
                outv[i][4] = fmaf(s, v1.x, outv[i][4]);
                outv[i][5] = fmaf(s, v1.y, outv[i][5]);
                outv[i][6] = fmaf(s, v1.z, outv[i][6]);
                outv[i][7] = fmaf(s, v1.w, outv[i][7]);
            }
        }
        __syncthreads();   // before next chunk overwrites ks/vs/ss
    }

    // groupnorm over the 128-dim group (this block owns all of it per q-row)
    #pragma unroll
    for (int i = 0; i < 4; i++) {
        float s1 = 0.f, s2 = 0.f;
        #pragma unroll
        for (int j = 0; j < 8; j++) { s1 += outv[i][j]; s2 += outv[i][j] * outv[i][j]; }
        ss[ty * 4 + i][tx]      = s1;
        ss[ty * 4 + i][16 + tx] = s2;
    }
    __syncthreads();
    if (tid < QT) {
        float s1 = 0.f, s2 = 0.f;
        #pragma unroll
        for (int t = 0; t < 16; t++) { s1 += ss[tid][t]; s2 += ss[tid][16 + t]; }
        const float mean = s1 * (1.f / 128.f);
        const float var  = s2 * (1.f / 128.f) - mean * mean;
        redm[tid] = mean;
        redi[tid] = 1.f / sqrtf(var + 1e-5f);
    }
    __syncthreads();

    const int cbase = h * HD;
    #pragma unroll
    for (int i = 0; i < 4; i++) {
        const int r = r0 + ty * 4 + i;
        const float mean = redm[ty * 4 + i];
        const float inv  = redi[ty * 4 + i];
        #pragma unroll
        for (int jh = 0; jh < 2; jh++) {
            const int c = cbase + tx * 4 + jh * 64;
            const float4 gw = *(const float4*)&gnw[c];
            const float4 gb = *(const float4*)&gnb[c];
            const float4 gg = *(const float4*)&gbuf[(size_t)r * HIDD + c];
            float4 o;
            o.x = ((outv[i][jh * 4 + 0] - mean) * inv * gw.x + gb.x) * silu_f(gg.x);
            o.y = ((outv[i][jh * 4 + 1] - mean) * inv * gw.y + gb.y) * silu_f(gg.y);
            o.z = ((outv[i][jh * 4 + 2] - mean) * inv * gw.z + gb.z) * silu_f(gg.z);
            o.w = ((outv[i][jh * 4 + 3] - mean) * inv * gw.w + gb.w) * silu_f(gg.w);
            *(float4*)&y[(size_t)r * HIDD + c] = o;
        }
    }
}

extern "C" void kernel_launch(void* const* d_in, const int* in_sizes, int n_in,
                              void* d_out, int out_size, void* d_ws, size_t ws_size,
                              hipStream_t stream) {
    const float* x   = (const float*)d_in[0];
    const int*   pid = (const int*)d_in[1];   // integer input -> const int* per harness
    const float* Wq  = (const float*)d_in[2];
    const float* Wk  = (const float*)d_in[3];
    const float* Wv  = (const float*)d_in[4];
    const float* Wg  = (const float*)d_in[5];
    const float* Wo  = (const float*)d_in[6];
    const float* gnw = (const float*)d_in[7];
    const float* gnb = (const float*)d_in[8];
    float* out = (float*)d_out;

    const size_t PLANE = (size_t)NHEAD * S_LEN * HD;  // 4,194,304 floats
    float* qh   = (float*)d_ws;
    float* kh   = qh + PLANE;
    float* vh   = kh + PLANE;
    float* gbuf = vh + PLANE;
    float* ybuf = gbuf + PLANE;                       // total 80 MiB of d_ws

    (void)in_sizes; (void)n_in; (void)out_size; (void)ws_size;

    // q/k/v/g projections + xpos, fused over the 4 weight matrices (8192 output cols)
    gemm_kernel<0><<<dim3(8192 / BN, S_LEN / BM), 256, 0, stream>>>(
        x, Wq, Wk, Wv, Wg, pid, qh, kh, vh, gbuf, nullptr);

    // retention + groupnorm + silu gate -> ybuf
    retention_kernel<<<dim3(S_LEN / 64, NHEAD), 256, 0, stream>>>(
        qh, kh, vh, gbuf, gnw, gnb, ybuf);

    // out = ybuf @ Wo
    gemm_kernel<1><<<dim3(HIDD / BN, S_LEN / BM), 256, 0, stream>>>(
        ybuf, Wo, Wo, Wo, Wo, pid, qh, kh, vh, gbuf, out);
}

// Round 2
// 1646.439 us; speedup vs baseline: 1.0438x; 1.0438x over previous
//
#include <hip/hip_runtime.h>
#include <math.h>

#define S_LEN 2048
#define HIDD  2048
#define NHEAD 16
#define HD    128

typedef __attribute__((ext_vector_type(8))) short short8;
typedef __attribute__((ext_vector_type(4))) float float4v;

static __device__ __forceinline__ unsigned short f2bf(float f) {
    unsigned int u = __float_as_uint(f);
    u += 0x7fff + ((u >> 16) & 1);          // round-to-nearest-even
    return (unsigned short)(u >> 16);
}
static __device__ __forceinline__ float bf2f(unsigned short s) {
    return __uint_as_float(((unsigned int)s) << 16);
}
__device__ __forceinline__ float silu_f(float x) { return x / (1.f + expf(-x)); }

__device__ __forceinline__ void gl_lds16(const unsigned short* g, short* l) {
    __builtin_amdgcn_global_load_lds((const __attribute__((address_space(1))) void*)g,
                                     (__attribute__((address_space(3))) void*)l, 16, 0, 0);
}

// fp32 -> (hi, lo) bf16 planes, elementwise
__global__ __launch_bounds__(256)
void split_kernel(const float* __restrict__ in, unsigned short* __restrict__ hi,
                  unsigned short* __restrict__ lo, int n4)
{
    const int i = blockIdx.x * 256 + threadIdx.x;
    if (i >= n4) return;
    const float4 v = ((const float4*)in)[i];
    ushort4 h, l;
    h.x = f2bf(v.x); l.x = f2bf(v.x - bf2f(h.x));
    h.y = f2bf(v.y); l.y = f2bf(v.y - bf2f(h.y));
    h.z = f2bf(v.z); l.z = f2bf(v.z - bf2f(h.z));
    h.w = f2bf(v.w); l.w = f2bf(v.w - bf2f(h.w));
    ((ushort4*)hi)[i] = h;
    ((ushort4*)lo)[i] = l;
}

// W (K x N, f32) -> WT_hi, WT_lo (N x K, bf16)
__global__ __launch_bounds__(256)
void split_transpose(const float* __restrict__ W, unsigned short* __restrict__ Thi,
                     unsigned short* __restrict__ Tlo)
{
    __shared__ float t[64][65];
    const int k0 = blockIdx.y * 64, n0 = blockIdx.x * 64;
    const int tx = threadIdx.x & 15, ty = threadIdx.x >> 4;
    #pragma unroll
    for (int it = 0; it < 4; it++) {
        const int k = ty + it * 16;
        const float4 v = *(const float4*)&W[(size_t)(k0 + k) * HIDD + n0 + tx * 4];
        t[k][tx * 4 + 0] = v.x; t[k][tx * 4 + 1] = v.y;
        t[k][tx * 4 + 2] = v.z; t[k][tx * 4 + 3] = v.w;
    }
    __syncthreads();
    #pragma unroll
    for (int it = 0; it < 4; it++) {
        const int n = ty + it * 16;
        ushort4 h, l;
        float a;
        a = t[tx * 4 + 0][n]; h.x = f2bf(a); l.x = f2bf(a - bf2f(h.x));
        a = t[tx * 4 + 1][n]; h.y = f2bf(a); l.y = f2bf(a - bf2f(h.y));
        a = t[tx * 4 + 2][n]; h.z = f2bf(a); l.z = f2bf(a - bf2f(h.z));
        a = t[tx * 4 + 3][n]; h.w = f2bf(a); l.w = f2bf(a - bf2f(h.w));
        *(ushort4*)&Thi[(size_t)(n0 + n) * HIDD + k0 + tx * 4] = h;
        *(ushort4*)&Tlo[(size_t)(n0 + n) * HIDD + k0 + tx * 4] = l;
    }
}

// Split-bf16 MFMA GEMM, 128x128 tile, BK=32, global_load_lds staging, XOR-swizzled LDS.
// MODE 0: A = x planes, B = [WqT|WkT|WvT|WgT] planes; xpos epilogue on q/k; scatter q/k/v/g.
// MODE 1: A = y planes, B = WoT planes; plain fp32 store.
template<int MODE>
__global__ __launch_bounds__(256)
void mfma_gemm(const unsigned short* __restrict__ Ahi, const unsigned short* __restrict__ Alo,
               const unsigned short* __restrict__ WT,   // [matrix][hi|lo] planes of N x K bf16
               const int* __restrict__ pos_ids,
               float* __restrict__ qh, float* __restrict__ kh,
               float* __restrict__ vh, float* __restrict__ gbuf,
               float* __restrict__ outC)
{
    __shared__ __align__(16) short sm[16384];   // 4 planes x 128rows x 32k bf16 = 32 KB

    const int tid = threadIdx.x;
    const int w = tid >> 6, L = tid & 63;
    const int n0 = blockIdx.x * 128, m0 = blockIdx.y * 128;
    const size_t PL = (size_t)HIDD * HIDD;

    int sel, nn;
    const unsigned short *Bhi, *Blo;
    if (MODE == 0) {
        sel = n0 >> 11; nn = n0 & 2047;
        Bhi = WT + (size_t)sel * 2 * PL; Blo = Bhi + PL;
    } else {
        sel = -1; nn = n0;
        Bhi = WT; Blo = WT + PL;
    }

    // ---- staging setup: wave w stages plane w (0:Ahi 1:Alo 2:Bhi 3:Blo)
    const int srow = L >> 2;                      // row within 16-row issue group
    const int sq   = L & 3;                       // 16B quad slot in LDS
    const int qg   = sq ^ ((srow >> 1) & 3);      // XOR swizzle: which global quad this slot holds
    const unsigned short* pbase = (w == 0) ? Ahi : (w == 1) ? Alo : (w == 2) ? Bhi : Blo;
    const int rbase = (w < 2) ? m0 : nn;
    short* ldsw = sm + w * 4096;
    const size_t goff = (size_t)(rbase + srow) * HIDD + qg * 8;

    // ---- fragment read addresses (loop-invariant)
    const int wm = (w & 1) * 64, wn = (w >> 1) * 64;
    const int qd = L >> 4, lc = L & 15;
    int aoff[4], boff[4];
    #pragma unroll
    for (int i = 0; i < 4; i++) {
        const int r = wm + i * 16 + lc;
        aoff[i] = r * 32 + (qd ^ ((r >> 1) & 3)) * 8;
    }
    #pragma unroll
    for (int j = 0; j < 4; j++) {
        const int r = wn + j * 16 + lc;
        boff[j] = r * 32 + (qd ^ ((r >> 1) & 3)) * 8;
    }

    float4v acc[4][4];
    #pragma unroll
    for (int i = 0; i < 4; i++)
        #pragma unroll
        for (int j = 0; j < 4; j++)
            #pragma unroll
            for (int r = 0; r < 4; r++) acc[i][j][r] = 0.f;

    for (int k0 = 0; k0 < HIDD; k0 += 32) {
        const unsigned short* g = pbase + goff + k0;
        #pragma unroll
        for (int t = 0; t < 8; t++)
            gl_lds16(g + (size_t)t * 16 * HIDD, ldsw + t * 512);
        __syncthreads();    // drains vmcnt before barrier (m97 semantics)

        short8 bhf[4], blf[4];
        #pragma unroll
        for (int j = 0; j < 4; j++) {
            bhf[j] = *(const short8*)(sm + 8192  + boff[j]);
            blf[j] = *(const short8*)(sm + 12288 + boff[j]);
        }
        #pragma unroll
        for (int i = 0; i < 4; i++) {
            const short8 ahf = *(const short8*)(sm + aoff[i]);
            const short8 alf = *(const short8*)(sm + 4096 + aoff[i]);
            #pragma unroll
            for (int j = 0; j < 4; j++) {
                acc[i][j] = __builtin_amdgcn_mfma_f32_16x16x32_bf16(ahf, bhf[j], acc[i][j], 0, 0, 0);
                acc[i][j] = __builtin_amdgcn_mfma_f32_16x16x32_bf16(alf, bhf[j], acc[i][j], 0, 0, 0);
                acc[i][j] = __builtin_amdgcn_mfma_f32_16x16x32_bf16(ahf, blf[j], acc[i][j], 0, 0, 0);
            }
        }
        __syncthreads();    // protect LDS before next stage
    }

    // ---- epilogue. D layout: row = qd*4+reg (m), col = lc (n)  [m89-verified]
    if (MODE == 1) {
        #pragma unroll
        for (int i = 0; i < 4; i++)
            #pragma unroll
            for (int r = 0; r < 4; r++) {
                const int row = m0 + wm + i * 16 + qd * 4 + r;
                #pragma unroll
                for (int j = 0; j < 4; j++)
                    outC[(size_t)row * HIDD + n0 + wn + j * 16 + lc] = acc[i][j][r];
            }
        return;
    }

    if (sel >= 2) {
        #pragma unroll
        for (int i = 0; i < 4; i++)
            #pragma unroll
            for (int r = 0; r < 4; r++) {
                const int row = m0 + wm + i * 16 + qd * 4 + r;
                #pragma unroll
                for (int j = 0; j < 4; j++) {
                    const int colloc = wn + j * 16 + lc;
                    const float v = acc[i][j][r];
                    if (sel == 2) {
                        const int h = nn >> 7;
                        vh[((size_t)h * S_LEN + row) * HD + colloc] = v;
                    } else {
                        gbuf[(size_t)row * HIDD + nn + colloc] = v;
                    }
                }
            }
    } else {
        // q/k: xpos rotary + scale. Pair partner (d^1) lives in lane L^1.
        float invf[4], lxs[4];
        int dj[4];
        #pragma unroll
        for (int j = 0; j < 4; j++) {
            const int d = wn + j * 16 + lc;
            dj[j] = d;
            const int p2 = d & ~1;      // 2*p
            invf[j] = exp2f(-(float)p2 * (13.28771238f / 128.f));       // 10000^(-2p/128)
            lxs[j]  = log2f(((float)p2 + 51.2f) * (1.f / 179.2f));      // log2(xpos_scale[p])
        }
        const float sgn = (sel == 0) ? 1.f : -1.f;
        float* dst = (sel == 0) ? qh : kh;
        const int h = nn >> 7;
        #pragma unroll
        for (int i = 0; i < 4; i++)
            #pragma unroll
            for (int r = 0; r < 4; r++) {
                const int row = m0 + wm + i * 16 + qd * 4 + r;
                const float pos = (float)pos_ids[row];
                const float pe = sgn * pos * (1.f / 512.f);
                #pragma unroll
                for (int j = 0; j < 4; j++) {
                    const float v = acc[i][j][r];
                    const float partner = __shfl_xor(v, 1);
                    float s, c; sincosf(pos * invf[j], &s, &c);
                    const float rot = (dj[j] & 1) ? partner : -partner;
                    const float e = (v * c + rot * s) * exp2f(lxs[j] * pe);
                    dst[((size_t)h * S_LEN + row) * HD + dj[j]] = e;
                }
            }
    }
}

// Retention (causal decayed attention) + fused groupnorm + silu gate -> split-bf16 y planes.
__global__ __launch_bounds__(256)
void retention_kernel(const float* __restrict__ qh, const float* __restrict__ kh,
                      const float* __restrict__ vh, const float* __restrict__ gbuf,
                      const float* __restrict__ gnw, const float* __restrict__ gnb,
                      unsigned short* __restrict__ yhi, unsigned short* __restrict__ ylo)
{
    constexpr int QT = 64, KT = 32;
    __shared__ float qs[QT][HD + 4];
    __shared__ float ks[KT][HD + 4];
    __shared__ float vs[KT][HD];
    __shared__ float ss[QT][KT + 1];
    __shared__ float redm[QT], redi[QT];

    const int h  = blockIdx.y;
    const int qb = (gridDim.x - 1) - blockIdx.x;   // heavy causal blocks dispatch first
    const int r0 = qb * QT;
    const int tid = threadIdx.x;
    const int tx = tid & 15, ty = tid >> 4;

    const float e  = -3.4657359f + (float)h * ((-6.2383246f + 3.4657359f) / 15.f);
    const float lg = logf(1.f - expf(e));

    const float* qbase = qh + ((size_t)h * S_LEN + r0) * HD;
    for (int f4 = tid; f4 < QT * HD / 4; f4 += 256) {
        const int row = f4 >> 5, c = (f4 & 31) * 4;
        *(float4*)&qs[row][c] = *(const float4*)&qbase[row * HD + c];
    }

    float outv[4][8];
    #pragma unroll
    for (int i = 0; i < 4; i++)
        #pragma unroll
        for (int j = 0; j < 8; j++) outv[i][j] = 0.f;

    const float* kbase = kh + (size_t)h * S_LEN * HD;
    const float* vbase = vh + (size_t)h * S_LEN * HD;
    const int nch = (r0 + QT) / KT;

    __syncthreads();
    for (int ch = 0; ch < nch; ch++) {
        const int kg0 = ch * KT;
        for (int f4 = tid; f4 < KT * HD / 4; f4 += 256) {
            const int row = f4 >> 5, c = (f4 & 31) * 4;
            *(float4*)&ks[row][c] = *(const float4*)&kbase[(size_t)(kg0 + row) * HD + c];
            *(float4*)&vs[row][c] = *(const float4*)&vbase[(size_t)(kg0 + row) * HD + c];
        }
        __syncthreads();

        float sc[4][2] = {{0.f, 0.f}, {0.f, 0.f}, {0.f, 0.f}, {0.f, 0.f}};
        #pragma unroll 4
        for (int d = 0; d < HD; d += 4) {
            const float4 k0 = *(const float4*)&ks[tx * 2][d];
            const float4 k1 = *(const float4*)&ks[tx * 2 + 1][d];
            #pragma unroll
            for (int i = 0; i < 4; i++) {
                const float4 qv = *(const float4*)&qs[ty * 4 + i][d];
                sc[i][0] = fmaf(qv.x, k0.x, fmaf(qv.y, k0.y, fmaf(qv.z, k0.z, fmaf(qv.w, k0.w, sc[i][0]))));
                sc[i][1] = fmaf(qv.x, k1.x, fmaf(qv.y, k1.y, fmaf(qv.z, k1.z, fmaf(qv.w, k1.w, sc[i][1]))));
            }
        }
        #pragma unroll
        for (int i = 0; i < 4; i++) {
            const int qg = r0 + ty * 4 + i;
            #pragma unroll
            for (int j = 0; j < 2; j++) {
                const int kg = kg0 + tx * 2 + j;
                const int dq = qg - kg;
                const float dec = (dq >= 0) ? __expf(lg * (float)dq) : 0.f;
                ss[ty * 4 + i][tx * 2 + j] = sc[i][j] * dec;
            }
        }
        __syncthreads();

        #pragma unroll 4
        for (int k = 0; k < KT; k++) {
            const float4 v0 = *(const float4*)&vs[k][tx * 4];
            const float4 v1 = *(const float4*)&vs[k][tx * 4 + 64];
            #pragma unroll
            for (int i = 0; i < 4; i++) {
                const float s = ss[ty * 4 + i][k];
                outv[i][0] = fmaf(s, v0.x, outv[i][0]);
                outv[i][1] = fmaf(s, v0.y, outv[i][1]);
                outv[i][2] = fmaf(s, v0.z, outv[i][2]);
                outv[i][3] = fmaf(s, v0.w, outv[i][3]);
                outv[i][4] = fmaf(s, v1.x, outv[i][4]);
                outv[i][5] = fmaf(s, v1.y, outv[i][5]);
                outv[i][6] = fmaf(s, v1.z, outv[i][6]);
                outv[i][7] = fmaf(s, v1.w, outv[i][7]);
            }
        }
        __syncthreads();
    }

    #pragma unroll
    for (int i = 0; i < 4; i++) {
        float s1 = 0.f, s2 = 0.f;
        #pragma unroll
        for (int j = 0; j < 8; j++) { s1 += outv[i][j]; s2 += outv[i][j] * outv[i][j]; }
        ss[ty * 4 + i][tx]      = s1;
        ss[ty * 4 + i][16 + tx] = s2;
    }
    __syncthreads();
    if (tid < QT) {
        float s1 = 0.f, s2 = 0.f;
        #pragma unroll
        for (int t = 0; t < 16; t++) { s1 += ss[tid][t]; s2 += ss[tid][16 + t]; }
        const float mean = s1 * (1.f / 128.f);
        const float var  = s2 * (1.f / 128.f) - mean * mean;
        redm[tid] = mean;
        redi[tid] = 1.f / sqrtf(var + 1e-5f);
    }
    __syncthreads();

    const int cbase = h * HD;
    #pragma unroll
    for (int i = 0; i < 4; i++) {
        const int r = r0 + ty * 4 + i;
        const float mean = redm[ty * 4 + i];
        const float inv  = redi[ty * 4 + i];
        #pragma unroll
        for (int jh = 0; jh < 2; jh++) {
            const int c = cbase + tx * 4 + jh * 64;
            const float4 gw = *(const float4*)&gnw[c];
            const float4 gb = *(const float4*)&gnb[c];
            const float4 gg = *(const float4*)&gbuf[(size_t)r * HIDD + c];
            float o0 = ((outv[i][jh * 4 + 0] - mean) * inv * gw.x + gb.x) * silu_f(gg.x);
            float o1 = ((outv[i][jh * 4 + 1] - mean) * inv * gw.y + gb.y) * silu_f(gg.y);
            float o2 = ((outv[i][jh * 4 + 2] - mean) * inv * gw.z + gb.z) * silu_f(gg.z);
            float o3 = ((outv[i][jh * 4 + 3] - mean) * inv * gw.w + gb.w) * silu_f(gg.w);
            ushort4 hv, lv;
            hv.x = f2bf(o0); lv.x = f2bf(o0 - bf2f(hv.x));
            hv.y = f2bf(o1); lv.y = f2bf(o1 - bf2f(hv.y));
            hv.z = f2bf(o2); lv.z = f2bf(o2 - bf2f(hv.z));
            hv.w = f2bf(o3); lv.w = f2bf(o3 - bf2f(hv.w));
            *(ushort4*)&yhi[(size_t)r * HIDD + c] = hv;
            *(ushort4*)&ylo[(size_t)r * HIDD + c] = lv;
        }
    }
}

extern "C" void kernel_launch(void* const* d_in, const int* in_sizes, int n_in,
                              void* d_out, int out_size, void* d_ws, size_t ws_size,
                              hipStream_t stream) {
    const float* x   = (const float*)d_in[0];
    const int*   pid = (const int*)d_in[1];
    const float* W[5] = {(const float*)d_in[2], (const float*)d_in[3], (const float*)d_in[4],
                         (const float*)d_in[5], (const float*)d_in[6]};   // Wq Wk Wv Wg Wo
    const float* gnw = (const float*)d_in[7];
    const float* gnb = (const float*)d_in[8];
    float* out = (float*)d_out;
    (void)in_sizes; (void)n_in; (void)out_size; (void)ws_size;

    const size_t PL = (size_t)HIDD * HIDD;   // 4,194,304 elements

    unsigned short* wt  = (unsigned short*)d_ws;      // 10 bf16 planes (5 matrices x hi/lo) = 80 MiB
    unsigned short* xhi = wt + 10 * PL;
    unsigned short* xlo = xhi + PL;                   // +16 MiB
    float* qh   = (float*)(xlo + PL);                 // 4 fp32 planes = 64 MiB
    float* kh   = qh + PL;
    float* vh   = kh + PL;
    float* gbuf = vh + PL;
    unsigned short* yhi = (unsigned short*)(gbuf + PL);  // +16 MiB  (total 176 MiB)
    unsigned short* ylo = yhi + PL;

    split_kernel<<<(int)(PL / 4 / 256), 256, 0, stream>>>(x, xhi, xlo, (int)(PL / 4));
    for (int m = 0; m < 5; m++)
        split_transpose<<<dim3(32, 32), 256, 0, stream>>>(W[m], wt + (size_t)m * 2 * PL,
                                                          wt + (size_t)m * 2 * PL + PL);

    // q/k/v/g projections + xpos (N = 8192 over 4 matrices)
    mfma_gemm<0><<<dim3(64, 16), 256, 0, stream>>>(xhi, xlo, wt, pid, qh, kh, vh, gbuf, nullptr);

    // retention + groupnorm + silu gate -> split y planes
    retention_kernel<<<dim3(32, 16), 256, 0, stream>>>(qh, kh, vh, gbuf, gnw, gnb, yhi, ylo);

    // out = y @ Wo
    mfma_gemm<1><<<dim3(16, 16), 256, 0, stream>>>(yhi, ylo, wt + 8 * PL, pid,
                                                   nullptr, nullptr, nullptr, nullptr, out);
}